// Round 2
// baseline (288.090 us; speedup 1.0000x reference)
//
#include <hip/hip_runtime.h>
#include <math.h>

#define NUM_K 524288
#define NUM_A 64

// Hardware transcendentals: v_log_f32 is log2(x), v_exp_f32 is 2^x.
#if defined(__has_builtin)
#if __has_builtin(__builtin_amdgcn_logf)
#define FAST_LOG2(x) __builtin_amdgcn_logf(x)
#endif
#if __has_builtin(__builtin_amdgcn_exp2f)
#define FAST_EXP2(x) __builtin_amdgcn_exp2f(x)
#endif
#endif
#ifndef FAST_LOG2
#define FAST_LOG2(x) log2f(x)
#endif
#ifndef FAST_EXP2
#define FAST_EXP2(x) exp2f(x)
#endif

// Kernel 1: w_k = theta_k * exp2( sum_i delta[k,i]*log2(alpha[k,i]) )
// 16 lanes cooperate per rule; each lane float4-loads 4 features -> coalesced.
__global__ __launch_bounds__(256) void rule_w_kernel(
    const float* __restrict__ alpha,
    const float* __restrict__ theta,
    const float* __restrict__ delta,
    float* __restrict__ out,
    float* __restrict__ total)
{
    const int tid  = threadIdx.x;
    const int sub  = tid & 15;                    // lane within 16-lane group
    const int grp  = tid >> 4;                    // group index within block
    const int groupsPerBlock = blockDim.x >> 4;   // 16
    const int stride = gridDim.x * groupsPerBlock;

    float wacc = 0.f;

    for (int k = blockIdx.x * groupsPerBlock + grp; k < NUM_K; k += stride) {
        const int base = k * NUM_A + sub * 4;
        const float4 a = *reinterpret_cast<const float4*>(alpha + base);
        const float4 d = *reinterpret_cast<const float4*>(delta + base);

        float s = FAST_LOG2(a.x) * d.x
                + FAST_LOG2(a.y) * d.y
                + FAST_LOG2(a.z) * d.z
                + FAST_LOG2(a.w) * d.w;

        // butterfly reduce across the 16-lane group (stays within the wave)
        s += __shfl_xor(s, 1);
        s += __shfl_xor(s, 2);
        s += __shfl_xor(s, 4);
        s += __shfl_xor(s, 8);

        if (sub == 0) {
            float w = theta[k] * FAST_EXP2(s);
            out[k] = w;
            wacc  += w;
        }
    }

    // reduce wacc across the full wave (non-leader lanes contribute 0)
    #pragma unroll
    for (int off = 1; off < 64; off <<= 1)
        wacc += __shfl_xor(wacc, off);

    __shared__ float waveSums[4];
    const int wid = tid >> 6;
    if ((tid & 63) == 0) waveSums[wid] = wacc;
    __syncthreads();
    if (tid == 0) {
        float bs = waveSums[0] + waveSums[1] + waveSums[2] + waveSums[3];
        atomicAdd(total, bs);
    }
}

// Kernel 2: out[k] *= 1/total, float4-vectorized in-place.
__global__ __launch_bounds__(256) void norm_kernel(
    float* __restrict__ out,
    const float* __restrict__ total)
{
    const float inv = 1.0f / total[0];
    const int idx = blockIdx.x * blockDim.x + threadIdx.x;   // one float4 each
    if (idx * 4 < NUM_K) {
        float4 v = *reinterpret_cast<float4*>(out + idx * 4);
        v.x *= inv; v.y *= inv; v.z *= inv; v.w *= inv;
        *reinterpret_cast<float4*>(out + idx * 4) = v;
    }
}

extern "C" void kernel_launch(void* const* d_in, const int* in_sizes, int n_in,
                              void* d_out, int out_size, void* d_ws, size_t ws_size,
                              hipStream_t stream) {
    const float* alpha = (const float*)d_in[0];
    const float* theta = (const float*)d_in[1];
    const float* delta = (const float*)d_in[2];
    float* out   = (float*)d_out;
    float* total = (float*)d_ws;

    // zero the accumulator (ws is re-poisoned to 0xAA before every launch)
    (void)hipMemsetAsync(total, 0, sizeof(float), stream);

    const int threads = 256;
    const int blocks1 = 2048;                    // grid-stride, 16 rules/blk-iter
    rule_w_kernel<<<blocks1, threads, 0, stream>>>(alpha, theta, delta, out, total);

    const int nVec = NUM_K / 4;                  // 131072 float4s
    const int blocks2 = (nVec + threads - 1) / threads;
    norm_kernel<<<blocks2, threads, 0, stream>>>(out, total);
    (void)in_sizes; (void)n_in; (void)out_size; (void)ws_size;
}

// Round 4
// 285.443 us; speedup vs baseline: 1.0093x; 1.0093x over previous
//
#include <hip/hip_runtime.h>
#include <math.h>

#define NUM_K 524288
#define NUM_A 64

// Hardware transcendentals: v_log_f32 is log2(x), v_exp_f32 is 2^x.
#if defined(__has_builtin)
#if __has_builtin(__builtin_amdgcn_logf)
#define FAST_LOG2(x) __builtin_amdgcn_logf(x)
#endif
#if __has_builtin(__builtin_amdgcn_exp2f)
#define FAST_EXP2(x) __builtin_amdgcn_exp2f(x)
#endif
#endif
#ifndef FAST_LOG2
#define FAST_LOG2(x) log2f(x)
#endif
#ifndef FAST_EXP2
#define FAST_EXP2(x) exp2f(x)
#endif

// Kernel 1: w_k = theta_k * exp2( sum_i delta[k,i]*log2(alpha[k,i]) )
// 16 lanes cooperate per rule. 4-rule unroll: 8 float4 loads in flight per
// iteration (8 KB/wave) to drive memory-level parallelism; the 4 butterfly
// chains are independent and pipeline through the DS unit.
__global__ __launch_bounds__(256) void rule_w_kernel(
    const float* __restrict__ alpha,
    const float* __restrict__ theta,
    const float* __restrict__ delta,
    float* __restrict__ out,
    float* __restrict__ total)
{
    const int tid = threadIdx.x;
    const int sub = tid & 15;                 // lane within 16-lane group
    const int grp = tid >> 4;                 // group index within block (0..15)
    const int S   = gridDim.x * 16;           // rule stride per unroll slot

    float wacc = 0.f;

    // NUM_K / (4*S) iterations; with 2048 blocks: S=32768, 4 iterations.
    for (int k = blockIdx.x * 16 + grp; k < NUM_K; k += 4 * S) {
        int kk[4];
        float4 a[4], d[4];
        float t[4], s[4];

        // issue all 8 vector loads up-front (independent, coalesced 1KB/wave each)
        #pragma unroll
        for (int j = 0; j < 4; ++j) {
            kk[j] = k + j * S;
            const int base = kk[j] * NUM_A + sub * 4;
            a[j] = *reinterpret_cast<const float4*>(alpha + base);
            d[j] = *reinterpret_cast<const float4*>(delta + base);
        }
        #pragma unroll
        for (int j = 0; j < 4; ++j) t[j] = theta[kk[j]];

        #pragma unroll
        for (int j = 0; j < 4; ++j) {
            s[j] = FAST_LOG2(a[j].x) * d[j].x
                 + FAST_LOG2(a[j].y) * d[j].y
                 + FAST_LOG2(a[j].z) * d[j].z
                 + FAST_LOG2(a[j].w) * d[j].w;
        }

        // 4 interleaved butterfly reductions across the 16-lane groups
        #pragma unroll
        for (int off = 1; off <= 8; off <<= 1) {
            #pragma unroll
            for (int j = 0; j < 4; ++j) s[j] += __shfl_xor(s[j], off);
        }

        if (sub == 0) {
            #pragma unroll
            for (int j = 0; j < 4; ++j) {
                float w = t[j] * FAST_EXP2(s[j]);
                out[kk[j]] = w;
                wacc += w;
            }
        }
    }

    // reduce wacc across the full wave (non-leader lanes contribute 0)
    #pragma unroll
    for (int off = 1; off < 64; off <<= 1)
        wacc += __shfl_xor(wacc, off);

    __shared__ float waveSums[4];
    const int wid = tid >> 6;
    if ((tid & 63) == 0) waveSums[wid] = wacc;
    __syncthreads();
    if (tid == 0) {
        float bs = waveSums[0] + waveSums[1] + waveSums[2] + waveSums[3];
        atomicAdd(total, bs);
    }
}

// Kernel 2: out[k] *= 1/total, float4-vectorized in-place.
__global__ __launch_bounds__(256) void norm_kernel(
    float* __restrict__ out,
    const float* __restrict__ total)
{
    const float inv = 1.0f / total[0];
    const int idx = blockIdx.x * blockDim.x + threadIdx.x;   // one float4 each
    if (idx * 4 < NUM_K) {
        float4 v = *reinterpret_cast<float4*>(out + idx * 4);
        v.x *= inv; v.y *= inv; v.z *= inv; v.w *= inv;
        *reinterpret_cast<float4*>(out + idx * 4) = v;
    }
}

extern "C" void kernel_launch(void* const* d_in, const int* in_sizes, int n_in,
                              void* d_out, int out_size, void* d_ws, size_t ws_size,
                              hipStream_t stream) {
    const float* alpha = (const float*)d_in[0];
    const float* theta = (const float*)d_in[1];
    const float* delta = (const float*)d_in[2];
    float* out   = (float*)d_out;
    float* total = (float*)d_ws;

    // zero the accumulator (ws is re-poisoned to 0xAA before every launch)
    (void)hipMemsetAsync(total, 0, sizeof(float), stream);

    const int threads = 256;
    const int blocks1 = 2048;   // 8 blocks/CU -> 32 waves/CU resident
    rule_w_kernel<<<blocks1, threads, 0, stream>>>(alpha, theta, delta, out, total);

    const int nVec = NUM_K / 4; // 131072 float4s
    const int blocks2 = (nVec + threads - 1) / threads;
    norm_kernel<<<blocks2, threads, 0, stream>>>(out, total);
    (void)in_sizes; (void)n_in; (void)out_size; (void)ws_size;
}

// Round 6
// 268.144 us; speedup vs baseline: 1.0744x; 1.0645x over previous
//
#include <hip/hip_runtime.h>
#include <math.h>

#define NUM_K 524288
#define NUM_A 64

// Hardware transcendentals: v_log_f32 is log2(x), v_exp_f32 is 2^x.
#if defined(__has_builtin)
#if __has_builtin(__builtin_amdgcn_logf)
#define FAST_LOG2(x) __builtin_amdgcn_logf(x)
#endif
#if __has_builtin(__builtin_amdgcn_exp2f)
#define FAST_EXP2(x) __builtin_amdgcn_exp2f(x)
#endif
#endif
#ifndef FAST_LOG2
#define FAST_LOG2(x) log2f(x)
#endif
#ifndef FAST_EXP2
#define FAST_EXP2(x) exp2f(x)
#endif

// Native clang vector type — __builtin_nontemporal_load requires a pointer to
// scalar or vector-of-scalar (HIP_vector_type float4 is a struct -> rejected).
typedef float floatx4 __attribute__((ext_vector_type(4)));

// Non-temporal float4 load: global_load_dwordx4 with the nt bit ->
// no cache allocation on miss -> no L3 dirty-victim writebacks during the
// kernel (the harness's input-restore leaves L3 full of dirty input lines).
__device__ inline floatx4 nt_load4(const float* p) {
    return __builtin_nontemporal_load(reinterpret_cast<const floatx4*>(p));
}

// Kernel 1: w_k = theta_k * exp2( sum_i delta[k,i]*log2(alpha[k,i]) )
// 16 lanes cooperate per rule; 4-rule unroll keeps 8 KB/wave in flight.
__global__ __launch_bounds__(256) void rule_w_kernel(
    const float* __restrict__ alpha,
    const float* __restrict__ theta,
    const float* __restrict__ delta,
    float* __restrict__ out,
    float* __restrict__ total)
{
    const int tid = threadIdx.x;
    const int sub = tid & 15;                 // lane within 16-lane group
    const int grp = tid >> 4;                 // group index within block (0..15)
    const int S   = gridDim.x * 16;           // rule stride per unroll slot

    float wacc = 0.f;

    // With 2048 blocks: S=32768, 4 iterations of 4 slots.
    for (int k = blockIdx.x * 16 + grp; k < NUM_K; k += 4 * S) {
        int kk[4];
        floatx4 a[4], d[4];
        float t[4], s[4];

        // issue all 8 vector loads up-front (independent, coalesced, nt)
        #pragma unroll
        for (int j = 0; j < 4; ++j) {
            kk[j] = k + j * S;
            const int base = kk[j] * NUM_A + sub * 4;
            a[j] = nt_load4(alpha + base);
            d[j] = nt_load4(delta + base);
        }
        #pragma unroll
        for (int j = 0; j < 4; ++j)
            t[j] = __builtin_nontemporal_load(theta + kk[j]);

        #pragma unroll
        for (int j = 0; j < 4; ++j) {
            s[j] = FAST_LOG2(a[j].x) * d[j].x
                 + FAST_LOG2(a[j].y) * d[j].y
                 + FAST_LOG2(a[j].z) * d[j].z
                 + FAST_LOG2(a[j].w) * d[j].w;
        }

        // 4 interleaved butterfly reductions across the 16-lane groups
        #pragma unroll
        for (int off = 1; off <= 8; off <<= 1) {
            #pragma unroll
            for (int j = 0; j < 4; ++j) s[j] += __shfl_xor(s[j], off);
        }

        if (sub == 0) {
            #pragma unroll
            for (int j = 0; j < 4; ++j) {
                float w = t[j] * FAST_EXP2(s[j]);
                out[kk[j]] = w;
                wacc += w;
            }
        }
    }

    // reduce wacc across the full wave (non-leader lanes contribute 0)
    #pragma unroll
    for (int off = 1; off < 64; off <<= 1)
        wacc += __shfl_xor(wacc, off);

    __shared__ float waveSums[4];
    const int wid = tid >> 6;
    if ((tid & 63) == 0) waveSums[wid] = wacc;
    __syncthreads();
    if (tid == 0) {
        float bs = waveSums[0] + waveSums[1] + waveSums[2] + waveSums[3];
        atomicAdd(total, bs);
    }
}

// Kernel 2: out[k] *= 1/total, float4-vectorized in-place (regular cached
// loads — out was just written and is L2-hot).
__global__ __launch_bounds__(256) void norm_kernel(
    float* __restrict__ out,
    const float* __restrict__ total)
{
    const float inv = 1.0f / total[0];
    const int idx = blockIdx.x * blockDim.x + threadIdx.x;   // one float4 each
    if (idx * 4 < NUM_K) {
        float4 v = *reinterpret_cast<float4*>(out + idx * 4);
        v.x *= inv; v.y *= inv; v.z *= inv; v.w *= inv;
        *reinterpret_cast<float4*>(out + idx * 4) = v;
    }
}

extern "C" void kernel_launch(void* const* d_in, const int* in_sizes, int n_in,
                              void* d_out, int out_size, void* d_ws, size_t ws_size,
                              hipStream_t stream) {
    const float* alpha = (const float*)d_in[0];
    const float* theta = (const float*)d_in[1];
    const float* delta = (const float*)d_in[2];
    float* out   = (float*)d_out;
    float* total = (float*)d_ws;

    // zero the accumulator (ws is re-poisoned to 0xAA before every launch)
    (void)hipMemsetAsync(total, 0, sizeof(float), stream);

    const int threads = 256;
    const int blocks1 = 2048;   // 8 blocks/CU -> 32 waves/CU resident
    rule_w_kernel<<<blocks1, threads, 0, stream>>>(alpha, theta, delta, out, total);

    const int nVec = NUM_K / 4; // 131072 float4s
    const int blocks2 = (nVec + threads - 1) / threads;
    norm_kernel<<<blocks2, threads, 0, stream>>>(out, total);
    (void)in_sizes; (void)n_in; (void)out_size; (void)ws_size;
}

// Round 9
// 265.704 us; speedup vs baseline: 1.0843x; 1.0092x over previous
//
#include <hip/hip_runtime.h>
#include <math.h>

#define NUM_K 524288
#define NUM_A 64

// Hardware transcendentals: v_log_f32 is log2(x), v_exp_f32 is 2^x.
#if defined(__has_builtin)
#if __has_builtin(__builtin_amdgcn_logf)
#define FAST_LOG2(x) __builtin_amdgcn_logf(x)
#endif
#if __has_builtin(__builtin_amdgcn_exp2f)
#define FAST_EXP2(x) __builtin_amdgcn_exp2f(x)
#endif
#endif
#ifndef FAST_LOG2
#define FAST_LOG2(x) log2f(x)
#endif
#ifndef FAST_EXP2
#define FAST_EXP2(x) exp2f(x)
#endif

// Native clang vector type — __builtin_nontemporal_load requires a pointer to
// scalar or vector-of-scalar (HIP_vector_type float4 is a struct -> rejected).
typedef float floatx4 __attribute__((ext_vector_type(4)));

// Non-temporal float4 load: global_load_dwordx4 with the nt bit ->
// no cache allocation -> no L3 dirty-victim writebacks during the kernel
// (the harness's input-restore leaves L3 full of dirty input lines; round 6
// confirmed: removing the writeback interference cut rule_w 106 -> <77 us).
__device__ inline floatx4 nt_load4(const float* p) {
    return __builtin_nontemporal_load(reinterpret_cast<const floatx4*>(p));
}

#define UNROLL 8

// Kernel 1: w_k = theta_k * exp2( sum_i delta[k,i]*log2(alpha[k,i]) )
// 16 lanes cooperate per rule; 8-rule unroll keeps 16 KB/wave in flight.
__global__ __launch_bounds__(256) void rule_w_kernel(
    const float* __restrict__ alpha,
    const float* __restrict__ theta,
    const float* __restrict__ delta,
    float* __restrict__ out,
    float* __restrict__ total)
{
    const int tid = threadIdx.x;
    const int sub = tid & 15;                 // lane within 16-lane group
    const int grp = tid >> 4;                 // group index within block (0..15)
    const int S   = gridDim.x * 16;           // rule stride per unroll slot

    float wacc = 0.f;

    // With 2048 blocks: S=32768, 2 iterations of 8 slots.
    for (int k = blockIdx.x * 16 + grp; k < NUM_K; k += UNROLL * S) {
        int kk[UNROLL];
        floatx4 a[UNROLL], d[UNROLL];
        float t[UNROLL], s[UNROLL];

        // issue all 16 vector loads up-front (independent, coalesced, nt)
        #pragma unroll
        for (int j = 0; j < UNROLL; ++j) {
            kk[j] = k + j * S;
            const int base = kk[j] * NUM_A + sub * 4;
            a[j] = nt_load4(alpha + base);
            d[j] = nt_load4(delta + base);
        }
        #pragma unroll
        for (int j = 0; j < UNROLL; ++j)
            t[j] = __builtin_nontemporal_load(theta + kk[j]);

        #pragma unroll
        for (int j = 0; j < UNROLL; ++j) {
            s[j] = FAST_LOG2(a[j].x) * d[j].x
                 + FAST_LOG2(a[j].y) * d[j].y
                 + FAST_LOG2(a[j].z) * d[j].z
                 + FAST_LOG2(a[j].w) * d[j].w;
        }

        // interleaved butterfly reductions across the 16-lane groups
        #pragma unroll
        for (int off = 1; off <= 8; off <<= 1) {
            #pragma unroll
            for (int j = 0; j < UNROLL; ++j) s[j] += __shfl_xor(s[j], off);
        }

        if (sub == 0) {
            #pragma unroll
            for (int j = 0; j < UNROLL; ++j) {
                float w = t[j] * FAST_EXP2(s[j]);
                out[kk[j]] = w;
                wacc += w;
            }
        }
    }

    // reduce wacc across the full wave (non-leader lanes contribute 0)
    #pragma unroll
    for (int off = 1; off < 64; off <<= 1)
        wacc += __shfl_xor(wacc, off);

    __shared__ float waveSums[4];
    const int wid = tid >> 6;
    if ((tid & 63) == 0) waveSums[wid] = wacc;
    __syncthreads();
    if (tid == 0) {
        float bs = waveSums[0] + waveSums[1] + waveSums[2] + waveSums[3];
        atomicAdd(total, bs);
    }
}

// Kernel 2: out[k] *= 1/total, float4-vectorized in-place (regular cached
// loads — out was just written and is L2-hot).
__global__ __launch_bounds__(256) void norm_kernel(
    float* __restrict__ out,
    const float* __restrict__ total)
{
    const float inv = 1.0f / total[0];
    const int idx = blockIdx.x * blockDim.x + threadIdx.x;   // one float4 each
    if (idx * 4 < NUM_K) {
        float4 v = *reinterpret_cast<float4*>(out + idx * 4);
        v.x *= inv; v.y *= inv; v.z *= inv; v.w *= inv;
        *reinterpret_cast<float4*>(out + idx * 4) = v;
    }
}

extern "C" void kernel_launch(void* const* d_in, const int* in_sizes, int n_in,
                              void* d_out, int out_size, void* d_ws, size_t ws_size,
                              hipStream_t stream) {
    const float* alpha = (const float*)d_in[0];
    const float* theta = (const float*)d_in[1];
    const float* delta = (const float*)d_in[2];
    float* out   = (float*)d_out;
    float* total = (float*)d_ws;

    // zero the accumulator (ws is re-poisoned to 0xAA before every launch)
    (void)hipMemsetAsync(total, 0, sizeof(float), stream);

    const int threads = 256;
    const int blocks1 = 2048;   // 8 blocks/CU
    rule_w_kernel<<<blocks1, threads, 0, stream>>>(alpha, theta, delta, out, total);

    const int nVec = NUM_K / 4; // 131072 float4s
    const int blocks2 = (nVec + threads - 1) / threads;
    norm_kernel<<<blocks2, threads, 0, stream>>>(out, total);
    (void)in_sizes; (void)n_in; (void)out_size; (void)ws_size;
}